// Round 9
// baseline (279.964 us; speedup 1.0000x reference)
//
#include <hip/hip_runtime.h>
#include <hip/hip_bf16.h>
#include <cstdint>

#define HWP    4096
#define CDIM   256
#define KCODES 8192
#define NROWS  32768
#define SPLITS 8           // code-splits; split = bid & 7 -> one split per XCD
#define CPB    1024        // codes per block = KCODES / SPLITS
#define NSB    32          // sub-blocks of 32 codes per block

typedef _Float16 f16x8 __attribute__((ext_vector_type(8)));
typedef float    f32x4 __attribute__((ext_vector_type(4)));
typedef unsigned long long u64;

// ---- async global->LDS, 16B per lane; LDS dest = wave-uniform base + lane*16 ----
__device__ __forceinline__ void load16_to_lds(const void* g, void* s) {
    __builtin_amdgcn_global_load_lds(
        (const __attribute__((address_space(1))) void*)(uintptr_t)g,
        (__attribute__((address_space(3))) void*)(uintptr_t)s,
        16, 0, 0);
}

// u64 branch-free top-4 insert
__device__ __forceinline__ void ins4(u64 c, u64 k[4]) {
    u64 a;
    a = k[0] > c ? k[0] : c;  c = k[0] > c ? c : k[0];  k[0] = a;
    a = k[1] > c ? k[1] : c;  c = k[1] > c ? c : k[1];  k[1] = a;
    a = k[2] > c ? k[2] : c;  c = k[2] > c ? c : k[2];  k[2] = a;
    k[3] = k[3] > c ? k[3] : c;
}

__device__ __forceinline__ uint32_t umin_(uint32_t a, uint32_t b) { return a < b ? a : b; }
__device__ __forceinline__ uint32_t umax_(uint32_t a, uint32_t b) { return a > b ? a : b; }

// =============== Kernel 1: fused prep = transpose x (fp16+fp32) + cb fp16 =====
// Flat grid 4096: blocks 0..2047 transpose x; 2048..4095 convert codebook.
__global__ __launch_bounds__(256) void prep_kernel(const float* __restrict__ x,
                                                   const float* __restrict__ cb,
                                                   _Float16* __restrict__ xh,
                                                   float* __restrict__ xt,
                                                   _Float16* __restrict__ ch) {
    int bid = blockIdx.x;
    int t = threadIdx.x;
    if (bid >= 2048) {
        int i4 = (bid - 2048) * 256 + t;
        float4 v = ((const float4*)cb)[i4];
        alignas(8) _Float16 h[4];
        h[0] = (_Float16)v.x; h[1] = (_Float16)v.y;
        h[2] = (_Float16)v.z; h[3] = (_Float16)v.w;
        *(uint2*)(ch + (size_t)i4 * 4) = *(uint2*)h;
        return;
    }
    __shared__ float tile[64][65];
    int pb = bid & 63, cbk = (bid >> 6) & 3, b = bid >> 8;
    int p0 = pb * 64, c0 = cbk * 64;
    int pl = t & 63, cl = t >> 6;
    const float* src = x + ((size_t)b * CDIM + c0) * HWP + p0;
    #pragma unroll 4
    for (int i = 0; i < 16; ++i) {
        int c = cl * 16 + i;
        tile[c][pl] = src[(size_t)c * HWP + pl];
    }
    __syncthreads();
    int p = t >> 2, cq = (t & 3) * 16;
    size_t n = (size_t)b * HWP + p0 + p;
    alignas(16) _Float16 hbuf[16];
    alignas(16) float    fbuf[16];
    #pragma unroll
    for (int j = 0; j < 16; ++j) {
        float v = tile[cq + j][p];
        fbuf[j] = v;
        hbuf[j] = (_Float16)v;
    }
    *(int4*)(xh + n * CDIM + c0 + cq)     = ((int4*)hbuf)[0];
    *(int4*)(xh + n * CDIM + c0 + cq + 8) = ((int4*)hbuf)[1];
    #pragma unroll
    for (int j = 0; j < 4; ++j)
        *(float4*)(xt + n * CDIM + c0 + cq + j * 4) = ((float4*)fbuf)[j];
}

// =============== Kernel 2: A-in-registers fp16 MFMA GEMM, B streamed ==========
// ROUND-9: 3-buffer ring (48 KB) + COUNTED vmcnt + raw s_barrier (T3/T4).
// Round-8's __syncthreads compiled to vmcnt(0) drain -- it waited for the
// JUST-ISSUED tile-s+1 prefetch every iter (~450 stall cyc/iter-slot).
// New per-iter protocol (one barrier, no full drain):
//   s_waitcnt vmcnt(4)   ; tile s's 4 per-wave DMAs retired (vmcnt retire ==
//                        ; LDS write complete, m135); tile s+1's stay in flight
//   sched_barrier(0); s_barrier; sched_barrier(0)   ; cross-wave visibility +
//                        ; fence vs compiler hoisting ds_reads (rule #18)
//   issue DMA tile s+2 -> buf (s+2)%3   ; safe: all waves finished READING
//                        ; that buffer at iter s-1 before passing this barrier
//   compute tile s from buf s%3
// Last iter uses vmcnt(0). Exactly 4 vmem/wave/tile, no other in-loop vmem,
// so the hardcoded counts are exact. Key path unchanged from round 8
// (acc init 4608 free-bias + u32 shift-key + med3-fused top-2).
__global__ __launch_bounds__(256, 2) void gemm_kernel(const _Float16* __restrict__ xh,
                                                      const _Float16* __restrict__ ch,
                                                      uint2* __restrict__ ptop) {
    __shared__ _Float16 sB[3][32 * CDIM];          // 3 x 16 KB ring

    int t = threadIdx.x;
    int w = t >> 6, lane = t & 63;
    int cc2 = lane & 15, qq = lane >> 4;
    int bid = blockIdx.x;
    int split  = bid & 7;
    int rowblk = bid >> 3;
    int rw = rowblk * 256 + w * 64;                // wave row base
    int c0 = split * CPB;                          // code base

    // ---- A fragments: full K in registers (4 mi x 8 ks x f16x8) -------------
    f16x8 a[4][8];
    {
        const _Float16* ap = xh + (size_t)(rw + cc2) * CDIM + qq * 8;
        #pragma unroll
        for (int mi = 0; mi < 4; ++mi)
            #pragma unroll
            for (int ks = 0; ks < 8; ++ks)
                a[mi][ks] = *(const f16x8*)(ap + (size_t)(mi * 16) * CDIM + ks * 32);
    }

    // ---- staging geometry (slot-permuted, pre-swizzled global source) -------
    const int u_ = t >> 5;                         // 0..7
    const _Float16* sbs[4];
    #pragma unroll
    for (int it = 0; it < 4; ++it) {
        int rot   = it * 2 + (u_ >> 2);            // sigma>>2  (0..7)
        int wcode = ((u_ & 1) << 4) | (((u_ >> 1) & 1) << 3) | rot;
        int j     = (t & 31) ^ rot;
        sbs[it] = ch + (size_t)(c0 + wcode) * CDIM + j * 8;
    }
    char* dstw = (char*)&sB[0][0] + (w * 64) * 16;   // wave region in buffer 0

    // prologue: stage tiles 0,1 -> bufs 0,1; full drain once
    #pragma unroll
    for (int it = 0; it < 4; ++it) {
        load16_to_lds(sbs[it],                       dstw + it * 4096);
        load16_to_lds(sbs[it] + (size_t)(32 * CDIM), dstw + 16384 + it * 4096);
    }
    __syncthreads();

    // read-side lane constants
    const int sig2 = (cc2 & 7) * 4 + ((cc2 >> 3) << 1);   // sigma minus ni
    const int gx   = cc2 & 7;                             // xor spread
    const uint32_t tbase = (uint32_t)(1023 - ((cc2 >> 3) * 8 + (cc2 & 7)));

    uint32_t k1[4][4], k2[4][4];
    #pragma unroll
    for (int mi = 0; mi < 4; ++mi)
        #pragma unroll
        for (int r = 0; r < 4; ++r) { k1[mi][r] = 0u; k2[mi][r] = 0u; }

    const f32x4 init4608 = {4608.0f, 4608.0f, 4608.0f, 4608.0f};

    int rd = 0, wr = 2;
    #pragma unroll 2
    for (int s = 0; s < NSB; ++s) {
        if (s < NSB - 1) asm volatile("s_waitcnt vmcnt(4)" ::: "memory");
        else             asm volatile("s_waitcnt vmcnt(0)" ::: "memory");
        __builtin_amdgcn_sched_barrier(0);
        __builtin_amdgcn_s_barrier();
        __builtin_amdgcn_sched_barrier(0);

        // issue DMA for tile s+2 into ring slot wr (= (s+2)%3)
        if (s < NSB - 2) {
            size_t soff = (size_t)(s + 2) * (32 * CDIM);
            char* dst = dstw + wr * 16384;
            #pragma unroll
            for (int it = 0; it < 4; ++it)
                load16_to_lds(sbs[it] + soff, dst + it * 4096);
        }

        const char* bufB = (const char*)&sB[0][0] + rd * 16384;
        f32x4 acc[2][4];
        #pragma unroll
        for (int ni = 0; ni < 2; ++ni)
            #pragma unroll
            for (int mi = 0; mi < 4; ++mi) acc[ni][mi] = init4608;

        #pragma unroll
        for (int ks = 0; ks < 8; ++ks) {
            int g = (ks * 4 + qq) ^ gx;
            const char* bb = bufB + sig2 * 512 + g * 16;
            f16x8 bf0 = *(const f16x8*)(bb);
            f16x8 bf1 = *(const f16x8*)(bb + 512);
            acc[0][0] = __builtin_amdgcn_mfma_f32_16x16x32_f16(a[0][ks], bf0, acc[0][0], 0, 0, 0);
            acc[0][1] = __builtin_amdgcn_mfma_f32_16x16x32_f16(a[1][ks], bf0, acc[0][1], 0, 0, 0);
            acc[0][2] = __builtin_amdgcn_mfma_f32_16x16x32_f16(a[2][ks], bf0, acc[0][2], 0, 0, 0);
            acc[0][3] = __builtin_amdgcn_mfma_f32_16x16x32_f16(a[3][ks], bf0, acc[0][3], 0, 0, 0);
            acc[1][0] = __builtin_amdgcn_mfma_f32_16x16x32_f16(a[0][ks], bf1, acc[1][0], 0, 0, 0);
            acc[1][1] = __builtin_amdgcn_mfma_f32_16x16x32_f16(a[1][ks], bf1, acc[1][1], 0, 0, 0);
            acc[1][2] = __builtin_amdgcn_mfma_f32_16x16x32_f16(a[2][ks], bf1, acc[1][2], 0, 0, 0);
            acc[1][3] = __builtin_amdgcn_mfma_f32_16x16x32_f16(a[3][ks], bf1, acc[1][3], 0, 0, 0);
        }

        // u32 shift-keys; insert: k2' = max(k2, min(k1,p)), k1' = max(k1,p)
        uint32_t tag0 = tbase - (uint32_t)(s * 32);
        uint32_t tag1 = tag0 - 16u;
        #pragma unroll
        for (int mi = 0; mi < 4; ++mi)
            #pragma unroll
            for (int r = 0; r < 4; ++r) {
                uint32_t key0 = (__float_as_uint(acc[0][mi][r]) << 10) | tag0;
                uint32_t key1 = (__float_as_uint(acc[1][mi][r]) << 10) | tag1;
                uint32_t K1 = k1[mi][r], K2 = k2[mi][r];
                K2 = umax_(K2, umin_(K1, key0));
                K1 = umax_(K1, key0);
                K2 = umax_(K2, umin_(K1, key1));
                K1 = umax_(K1, key1);
                k1[mi][r] = K1;
                k2[mi][r] = K2;
            }

        rd = rd == 2 ? 0 : rd + 1;
        wr = wr == 2 ? 0 : wr + 1;
    }

    // cross-lane (16-code columns) top-2 merge + write one uint2 per row
    #pragma unroll
    for (int mi = 0; mi < 4; ++mi)
        #pragma unroll
        for (int r = 0; r < 4; ++r) {
            uint32_t K1 = k1[mi][r], K2 = k2[mi][r];
            #pragma unroll
            for (int msk = 1; msk <= 8; msk <<= 1) {
                uint32_t o1 = (uint32_t)__shfl_xor((int)K1, msk);
                uint32_t o2 = (uint32_t)__shfl_xor((int)K2, msk);
                K2 = umax_(umin_(K1, o1), umax_(K2, o2));
                K1 = umax_(K1, o1);
            }
            if (cc2 == 0) {
                int row = rw + mi * 16 + qq * 4 + r;
                ptop[(size_t)split * NROWS + row] = make_uint2(K1, K2);
            }
        }
}

// =============== Kernel 3: fused finalize = reduce + rescore + writeq =========
__global__ __launch_bounds__(256) void finalize_kernel(const uint2* __restrict__ ptop,
                                                       const float* __restrict__ xt,
                                                       const float* __restrict__ cb,
                                                       float* __restrict__ loss_sum,
                                                       unsigned* __restrict__ counter,
                                                       float* __restrict__ out) {
    __shared__ int4  scand[64];
    __shared__ int   swin[64];
    __shared__ float rows[64][260];       // pad 260 (16B-aligned rows)

    int bh = blockIdx.x;                  // b*64 + h
    int b = bh >> 6, h = bh & 63;
    int t = threadIdx.x;

    // ---- phase 1: per-row top-4 over 8 splits ----
    if (t < 64) {
        int n = bh * 64 + t;
        u64 k[4] = {0ull, 0ull, 0ull, 0ull};
        #pragma unroll
        for (int sp = 0; sp < SPLITS; ++sp) {
            uint2 e = ptop[(size_t)sp * NROWS + n];
            ins4(((u64)e.x << 3) | (unsigned)sp, k);
            ins4(((u64)e.y << 3) | (unsigned)sp, k);
        }
        int4 c4;
        int cc[4];
        #pragma unroll
        for (int j = 0; j < 4; ++j) {
            int sp       = (int)(k[j] & 7u);
            uint32_t key = (uint32_t)(k[j] >> 3);
            cc[j] = sp * CPB + 1023 - (int)(key & 1023u);
        }
        c4.x = cc[0]; c4.y = cc[1]; c4.z = cc[2]; c4.w = cc[3];
        scand[t] = c4;
    }
    __syncthreads();

    // ---- phase 2: exact rescore, 4 chunks of 16 rows ----
    int l = t & 63;
    int cl = t & 15;
    float lpacc = 0.f;
    for (int chunk = 0; chunk < 4; ++chunk) {
        int rloc = chunk * 16 + (t >> 4);
        int n = bh * 64 + rloc;
        int4 cd = scand[rloc];
        const float* xr = xt + (size_t)n * CDIM + cl * 16;
        const float* r0 = cb + (size_t)cd.x * CDIM + cl * 16;
        const float* r1 = cb + (size_t)cd.y * CDIM + cl * 16;
        const float* r2 = cb + (size_t)cd.z * CDIM + cl * 16;
        const float* r3 = cb + (size_t)cd.w * CDIM + cl * 16;
        float n2 = 0.f, d0 = 0.f, d1 = 0.f, d2 = 0.f, d3 = 0.f;
        #pragma unroll
        for (int chk = 0; chk < 4; ++chk) {
            float4 xv = *(const float4*)(xr + chk * 4);
            float4 a0 = *(const float4*)(r0 + chk * 4);
            float4 a1 = *(const float4*)(r1 + chk * 4);
            float4 a2 = *(const float4*)(r2 + chk * 4);
            float4 a3 = *(const float4*)(r3 + chk * 4);
            float xs[4] = {xv.x, xv.y, xv.z, xv.w};
            float b0[4] = {a0.x, a0.y, a0.z, a0.w};
            float b1[4] = {a1.x, a1.y, a1.z, a1.w};
            float b2[4] = {a2.x, a2.y, a2.z, a2.w};
            float b3[4] = {a3.x, a3.y, a3.z, a3.w};
            #pragma unroll
            for (int j = 0; j < 4; ++j) {
                n2 = fmaf(xs[j], xs[j], n2);
                d0 = fmaf(xs[j], b0[j], d0);
                d1 = fmaf(xs[j], b1[j], d1);
                d2 = fmaf(xs[j], b2[j], d2);
                d3 = fmaf(xs[j], b3[j], d3);
            }
        }
        #pragma unroll
        for (int m = 1; m <= 8; m <<= 1) {
            n2 += __shfl_xor(n2, m);
            d0 += __shfl_xor(d0, m);
            d1 += __shfl_xor(d1, m);
            d2 += __shfl_xor(d2, m);
            d3 += __shfl_xor(d3, m);
        }
        if (cl == 0) {
            float bD = d0; int bI = cd.x;
            if (d1 > bD || (d1 == bD && cd.y < bI)) { bD = d1; bI = cd.y; }
            if (d2 > bD || (d2 == bD && cd.z < bI)) { bD = d2; bI = cd.z; }
            if (d3 > bD || (d3 == bD && cd.w < bI)) { bD = d3; bI = cd.w; }
            swin[rloc] = bI;
            lpacc += bD / fmaxf(sqrtf(n2), 1e-12f);
        }
    }
    #pragma unroll
    for (int m = 1; m <= 32; m <<= 1) lpacc += __shfl_xor(lpacc, m);
    if (l == 0) atomicAdd(loss_sum, lpacc);
    __syncthreads();

    // ---- phase 3: gather q via LDS transpose + coalesced write ----
    int rr = t >> 6, cq = t & 63;
    #pragma unroll 4
    for (int i = 0; i < 16; ++i) {
        int wv = i * 4 + rr;
        int id = swin[wv];
        float4 v = *(const float4*)(cb + (size_t)id * CDIM + cq * 4);
        *(float4*)&rows[wv][cq * 4] = v;
    }
    __syncthreads();
    int wl = t & 63, cg = t >> 6;
    float* ob = out + (size_t)b * CDIM * HWP + h * 64 + wl;
    #pragma unroll 4
    for (int c = cg * 64; c < cg * 64 + 64; ++c)
        ob[(size_t)c * HWP] = rows[wl][c];

    // ---- last block writes the two loss scalars ----
    __syncthreads();
    if (t == 0) {
        __threadfence();
        unsigned prev = atomicAdd(counter, 1u);
        if (prev == 511u) {
            float total = atomicAdd(loss_sum, 0.0f);   // coherent read
            float mean = total / 32768.0f;
            out[8388608] = 0.25f * (1.0f - mean);
            out[8388609] = 1.0f  * (1.0f - mean);
        }
    }
}

extern "C" void kernel_launch(void* const* d_in, const int* in_sizes, int n_in,
                              void* d_out, int out_size, void* d_ws, size_t ws_size,
                              hipStream_t stream) {
    const float* x  = (const float*)d_in[0];   // [8,256,64,64]
    const float* cb = (const float*)d_in[1];   // [8192,256]
    float* out = (float*)d_out;

    char* ws = (char*)d_ws;
    _Float16* xh   = (_Float16*)(ws);                     // 16,777,216 B
    _Float16* ch   = (_Float16*)(ws + 16777216);          //  4,194,304 B
    float*    xt   = (float*)   (ws + 20971520);          // 33,554,432 B
    uint2*    ptop = (uint2*)   (ws + 54525952);          //  2,097,152 B
    float*    loss = (float*)   (ws + 71958528);          //          4 B
    unsigned* cnt  = (unsigned*)(ws + 71958532);          //          4 B

    hipMemsetAsync(loss, 0, 8, stream);                   // loss + counter
    prep_kernel    <<<4096, 256, 0, stream>>>(x, cb, xh, xt, ch);
    gemm_kernel    <<<1024, 256, 0, stream>>>(xh, ch, ptop);
    finalize_kernel<<<512,  256, 0, stream>>>(ptop, xt, cb, loss, cnt, out);
}